// Round 7
// baseline (202.920 us; speedup 1.0000x reference)
//
#include <hip/hip_runtime.h>

// Problem constants (reference setup_inputs: mask [64, 512, 896] f32)
#define B 64
#define H 512
#define W 896
#define W4 (W / 4)                  // 224 float4 per row
#define PIX (H * W)                 // 458752 per batch
#define VEC (PIX / 4)               // 114688 float4 per batch
#define TPB 256
#define PT 0.5f

// Reduce geometry: 16 slices/batch -> 1024 blocks, 28 float4/thread
#define SLICES_R 16
#define VEC_SLICE_R (VEC / SLICES_R)    // 7168
#define ITERS_R (VEC_SLICE_R / TPB)     // 28
#define NBLK_R (B * SLICES_R)           // 1024

// Fill geometry: 32 slices/batch -> 2048 blocks, 14 float4/thread
#define SLICES_F 32
#define VEC_SLICE_F (VEC / SLICES_F)    // 3584
#define ITERS_F (VEC_SLICE_F / TPB)     // 14
#define NBLK_F (B * SLICES_F)           // 2048

typedef float f32x4 __attribute__((ext_vector_type(4)));

// ws layout: int[5][NBLK_R] -> cnt, rmn, rmx, cmn, cmx partials, one slot per
// reduce-block (written exactly once -> no init kernel, no atomics needed).

static __device__ __forceinline__ f32x4 nt_load4(const f32x4* p) {
    return __builtin_nontemporal_load(p);
}
static __device__ __forceinline__ void nt_store4(f32x4* p, f32x4 v) {
    __builtin_nontemporal_store(v, p);
}

// ---------------------------------------------------------------------------
// Kernel 1: per-slice count + bbox partials.
// ---------------------------------------------------------------------------
__global__ __launch_bounds__(TPB) void rag_reduce_kernel(
        const float* __restrict__ mask, int* __restrict__ ws) {
    const int bid = blockIdx.x;          // 0..NBLK_R-1
    const int b   = bid >> 4;            // batch (SLICES_R == 16)
    const int tid = threadIdx.x;
    const int sbase = (bid & (SLICES_R - 1)) * VEC_SLICE_R + tid;

    const f32x4* m = reinterpret_cast<const f32x4*>(mask) + (size_t)b * VEC;

    int cnt = 0, rmn = H, rmx = -1, cmn = W, cmx = -1;

#pragma unroll
    for (int it = 0; it < ITERS_R; ++it) {
        const int i4 = sbase + it * TPB;
        const f32x4 v = nt_load4(&m[i4]);
        const bool f0 = v.x > PT;
        const bool f1 = v.y > PT;
        const bool f2 = v.z > PT;
        const bool f3 = v.w > PT;
        cnt += (int)f0 + (int)f1 + (int)f2 + (int)f3;
        if (f0 | f1 | f2 | f3) {
            const int row = i4 / W4;
            const int col = (i4 - row * W4) * 4;
            rmn = min(rmn, row);
            rmx = max(rmx, row);
            const int clo = f0 ? col : (f1 ? col + 1 : (f2 ? col + 2 : col + 3));
            const int chi = f3 ? col + 3 : (f2 ? col + 2 : (f1 ? col + 1 : col));
            cmn = min(cmn, clo);
            cmx = max(cmx, chi);
        }
    }

    // Wave-64 reduce.
#pragma unroll
    for (int off = 32; off > 0; off >>= 1) {
        cnt += __shfl_down(cnt, off);
        rmn = min(rmn, __shfl_down(rmn, off));
        rmx = max(rmx, __shfl_down(rmx, off));
        cmn = min(cmn, __shfl_down(cmn, off));
        cmx = max(cmx, __shfl_down(cmx, off));
    }

    __shared__ int s[5][TPB / 64];
    const int wave = tid >> 6;
    if ((tid & 63) == 0) {
        s[0][wave] = cnt; s[1][wave] = rmn; s[2][wave] = rmx;
        s[3][wave] = cmn; s[4][wave] = cmx;
    }
    __syncthreads();
    if (tid == 0) {
#pragma unroll
        for (int wv = 1; wv < TPB / 64; ++wv) {
            cnt += s[0][wv];
            rmn = min(rmn, s[1][wv]);
            rmx = max(rmx, s[2][wv]);
            cmn = min(cmn, s[3][wv]);
            cmx = max(cmx, s[4][wv]);
        }
        ws[0 * NBLK_R + bid] = cnt;
        ws[1 * NBLK_R + bid] = rmn;
        ws[2 * NBLK_R + bid] = rmx;
        ws[3 * NBLK_R + bid] = cmn;
        ws[4 * NBLK_R + bid] = cmx;
    }
}

// ---------------------------------------------------------------------------
// Kernel 2: finalize box from partials (first 16 lanes) + stream output.
// ---------------------------------------------------------------------------
__global__ __launch_bounds__(TPB) void rag_fill_kernel(
        const int* __restrict__ ws,
        const int* __restrict__ nthr_p,
        const int* __restrict__ dthr_p,
        float* __restrict__ out) {
    const int bid = blockIdx.x;
    const int b   = bid >> 5;            // SLICES_F == 32
    const int tid = threadIdx.x;

    __shared__ int sbox[4];
    if (tid < 64) {
        const int q = (b << 4) + (tid & 15);   // 16 partial slots for this batch
        int c  = ws[0 * NBLK_R + q];
        int r0 = ws[1 * NBLK_R + q];
        int r1 = ws[2 * NBLK_R + q];
        int c0 = ws[3 * NBLK_R + q];
        int c1 = ws[4 * NBLK_R + q];
#pragma unroll
        for (int off = 8; off > 0; off >>= 1) {
            c  += __shfl_xor(c, off, 16);
            r0 = min(r0, __shfl_xor(r0, off, 16));
            r1 = max(r1, __shfl_xor(r1, off, 16));
            c0 = min(c0, __shfl_xor(c0, off, 16));
            c1 = max(c1, __shfl_xor(c1, off, 16));
        }
        if (tid == 0) {
            const int nthr = *nthr_p;
            const int dthr = *dthr_p;
            int brmn, brmx, bcmn, bcmx;
            if (c >= nthr) {
                brmn = max(r0 - dthr, 0);
                brmx = min(r1 + dthr, H - 1);
                bcmn = max(c0 - dthr, 0);
                bcmx = min(c1 + dthr, W - 1);
            } else {  // too few points -> attend everywhere
                brmn = 0; brmx = H - 1; bcmn = 0; bcmx = W - 1;
            }
            sbox[0] = brmn; sbox[1] = brmx; sbox[2] = bcmn; sbox[3] = bcmx;
        }
    }
    __syncthreads();
    const int brmn = sbox[0];
    const unsigned rspan = (unsigned)(sbox[1] - brmn);   // brmx - brmn
    const int bcmn = sbox[2];
    const unsigned cspan = (unsigned)(sbox[3] - bcmn);   // bcmx - bcmn

    f32x4* ob = reinterpret_cast<f32x4*>(out) + (size_t)b * VEC;
    const int sbase = (bid & (SLICES_F - 1)) * VEC_SLICE_F + tid;

#pragma unroll
    for (int it = 0; it < ITERS_F; ++it) {
        const int i4 = sbase + it * TPB;
        const int row = i4 / W4;
        const int col = (i4 - row * W4) * 4;
        const bool rin = (unsigned)(row - brmn) <= rspan;
        f32x4 v;
        v.x = (rin & ((unsigned)(col + 0 - bcmn) <= cspan)) ? 1.0f : 0.0f;
        v.y = (rin & ((unsigned)(col + 1 - bcmn) <= cspan)) ? 1.0f : 0.0f;
        v.z = (rin & ((unsigned)(col + 2 - bcmn) <= cspan)) ? 1.0f : 0.0f;
        v.w = (rin & ((unsigned)(col + 3 - bcmn) <= cspan)) ? 1.0f : 0.0f;
        nt_store4(&ob[i4], v);
    }
}

// ---------------------------------------------------------------------------
extern "C" void kernel_launch(void* const* d_in, const int* in_sizes, int n_in,
                              void* d_out, int out_size, void* d_ws, size_t ws_size,
                              hipStream_t stream) {
    const float* mask = (const float*)d_in[0];
    const int*   nthr = (const int*)d_in[1];
    const int*   dthr = (const int*)d_in[2];
    float*       out  = (float*)d_out;
    int*         ws   = (int*)d_ws;

    rag_reduce_kernel<<<NBLK_R, TPB, 0, stream>>>(mask, ws);
    rag_fill_kernel<<<NBLK_F, TPB, 0, stream>>>(ws, nthr, dthr, out);
}

// Round 8
// 199.824 us; speedup vs baseline: 1.0155x; 1.0155x over previous
//
#include <hip/hip_runtime.h>

// Problem constants (reference setup_inputs: mask [64, 512, 896] f32)
#define B 64
#define H 512
#define W 896
#define W4 (W / 4)                  // 224 float4 per row
#define PIX (H * W)                 // 458752 per batch
#define VEC (PIX / 4)               // 114688 float4 per batch
#define TPB 512
#define PT 0.5f

// Both kernels: 16 slices/batch -> 1024 blocks of 512 threads, 14 float4/thread
#define SLICES 16
#define VEC_SLICE (VEC / SLICES)    // 7168 float4 per block
#define ITERS (VEC_SLICE / TPB)     // 14
#define NBLK (B * SLICES)           // 1024 blocks (4/CU, 32 waves/CU: fully resident)

typedef float f32x4 __attribute__((ext_vector_type(4)));

// ws layout: int[5][NBLK] -> cnt, rmn, rmx, cmn, cmx partials, one slot per
// reduce-block (written exactly once -> no init kernel, no atomics needed).

static __device__ __forceinline__ f32x4 nt_load4(const f32x4* p) {
    return __builtin_nontemporal_load(p);
}
static __device__ __forceinline__ void nt_store4(f32x4* p, f32x4 v) {
    __builtin_nontemporal_store(v, p);
}

// ---------------------------------------------------------------------------
// Kernel 1: per-slice count + bbox partials.
// ---------------------------------------------------------------------------
__global__ __launch_bounds__(TPB) void rag_reduce_kernel(
        const float* __restrict__ mask, int* __restrict__ ws) {
    const int bid = blockIdx.x;          // 0..NBLK-1
    const int b   = bid >> 4;            // batch (SLICES == 16)
    const int tid = threadIdx.x;
    const int sbase = (bid & (SLICES - 1)) * VEC_SLICE + tid;

    const f32x4* m = reinterpret_cast<const f32x4*>(mask) + (size_t)b * VEC;

    int cnt = 0, rmn = H, rmx = -1, cmn = W, cmx = -1;

#pragma unroll
    for (int it = 0; it < ITERS; ++it) {
        const int i4 = sbase + it * TPB;
        const f32x4 v = nt_load4(&m[i4]);
        const bool f0 = v.x > PT;
        const bool f1 = v.y > PT;
        const bool f2 = v.z > PT;
        const bool f3 = v.w > PT;
        cnt += (int)f0 + (int)f1 + (int)f2 + (int)f3;
        if (f0 | f1 | f2 | f3) {
            const int row = i4 / W4;
            const int col = (i4 - row * W4) * 4;
            rmn = min(rmn, row);
            rmx = max(rmx, row);
            const int clo = f0 ? col : (f1 ? col + 1 : (f2 ? col + 2 : col + 3));
            const int chi = f3 ? col + 3 : (f2 ? col + 2 : (f1 ? col + 1 : col));
            cmn = min(cmn, clo);
            cmx = max(cmx, chi);
        }
    }

    // Wave-64 reduce.
#pragma unroll
    for (int off = 32; off > 0; off >>= 1) {
        cnt += __shfl_down(cnt, off);
        rmn = min(rmn, __shfl_down(rmn, off));
        rmx = max(rmx, __shfl_down(rmx, off));
        cmn = min(cmn, __shfl_down(cmn, off));
        cmx = max(cmx, __shfl_down(cmx, off));
    }

    __shared__ int s[5][TPB / 64];
    const int wave = tid >> 6;
    if ((tid & 63) == 0) {
        s[0][wave] = cnt; s[1][wave] = rmn; s[2][wave] = rmx;
        s[3][wave] = cmn; s[4][wave] = cmx;
    }
    __syncthreads();
    if (tid == 0) {
#pragma unroll
        for (int wv = 1; wv < TPB / 64; ++wv) {
            cnt += s[0][wv];
            rmn = min(rmn, s[1][wv]);
            rmx = max(rmx, s[2][wv]);
            cmn = min(cmn, s[3][wv]);
            cmx = max(cmx, s[4][wv]);
        }
        ws[0 * NBLK + bid] = cnt;
        ws[1 * NBLK + bid] = rmn;
        ws[2 * NBLK + bid] = rmx;
        ws[3 * NBLK + bid] = cmn;
        ws[4 * NBLK + bid] = cmx;
    }
}

// ---------------------------------------------------------------------------
// Kernel 2: finalize box from partials (first 16 lanes) + stream output.
// ---------------------------------------------------------------------------
__global__ __launch_bounds__(TPB) void rag_fill_kernel(
        const int* __restrict__ ws,
        const int* __restrict__ nthr_p,
        const int* __restrict__ dthr_p,
        float* __restrict__ out) {
    const int bid = blockIdx.x;
    const int b   = bid >> 4;            // SLICES == 16
    const int tid = threadIdx.x;

    __shared__ int sbox[4];
    if (tid < 64) {
        const int q = (b << 4) + (tid & 15);   // 16 partial slots for this batch
        int c  = ws[0 * NBLK + q];
        int r0 = ws[1 * NBLK + q];
        int r1 = ws[2 * NBLK + q];
        int c0 = ws[3 * NBLK + q];
        int c1 = ws[4 * NBLK + q];
#pragma unroll
        for (int off = 8; off > 0; off >>= 1) {
            c  += __shfl_xor(c, off, 16);
            r0 = min(r0, __shfl_xor(r0, off, 16));
            r1 = max(r1, __shfl_xor(r1, off, 16));
            c0 = min(c0, __shfl_xor(c0, off, 16));
            c1 = max(c1, __shfl_xor(c1, off, 16));
        }
        if (tid == 0) {
            const int nthr = *nthr_p;
            const int dthr = *dthr_p;
            int brmn, brmx, bcmn, bcmx;
            if (c >= nthr) {
                brmn = max(r0 - dthr, 0);
                brmx = min(r1 + dthr, H - 1);
                bcmn = max(c0 - dthr, 0);
                bcmx = min(c1 + dthr, W - 1);
            } else {  // too few points -> attend everywhere
                brmn = 0; brmx = H - 1; bcmn = 0; bcmx = W - 1;
            }
            sbox[0] = brmn; sbox[1] = brmx; sbox[2] = bcmn; sbox[3] = bcmx;
        }
    }
    __syncthreads();
    const int brmn = sbox[0];
    const unsigned rspan = (unsigned)(sbox[1] - brmn);   // brmx - brmn
    const int bcmn = sbox[2];
    const unsigned cspan = (unsigned)(sbox[3] - bcmn);   // bcmx - bcmn

    f32x4* ob = reinterpret_cast<f32x4*>(out) + (size_t)b * VEC;
    const int sbase = (bid & (SLICES - 1)) * VEC_SLICE + tid;

#pragma unroll
    for (int it = 0; it < ITERS; ++it) {
        const int i4 = sbase + it * TPB;
        const int row = i4 / W4;
        const int col = (i4 - row * W4) * 4;
        const bool rin = (unsigned)(row - brmn) <= rspan;
        f32x4 v;
        v.x = (rin & ((unsigned)(col + 0 - bcmn) <= cspan)) ? 1.0f : 0.0f;
        v.y = (rin & ((unsigned)(col + 1 - bcmn) <= cspan)) ? 1.0f : 0.0f;
        v.z = (rin & ((unsigned)(col + 2 - bcmn) <= cspan)) ? 1.0f : 0.0f;
        v.w = (rin & ((unsigned)(col + 3 - bcmn) <= cspan)) ? 1.0f : 0.0f;
        nt_store4(&ob[i4], v);
    }
}

// ---------------------------------------------------------------------------
extern "C" void kernel_launch(void* const* d_in, const int* in_sizes, int n_in,
                              void* d_out, int out_size, void* d_ws, size_t ws_size,
                              hipStream_t stream) {
    const float* mask = (const float*)d_in[0];
    const int*   nthr = (const int*)d_in[1];
    const int*   dthr = (const int*)d_in[2];
    float*       out  = (float*)d_out;
    int*         ws   = (int*)d_ws;

    rag_reduce_kernel<<<NBLK, TPB, 0, stream>>>(mask, ws);
    rag_fill_kernel<<<NBLK, TPB, 0, stream>>>(ws, nthr, dthr, out);
}